// Round 15
// baseline (290.461 us; speedup 1.0000x reference)
//
#include <hip/hip_runtime.h>
#include <hip/hip_bf16.h>

// GCN node encoder: 3 layers GraphConv(norm=both) + residual linear + ReLU + BatchNorm.
// N=50000, E=500000, D=128, L=3.
// Round 26: delete the boff_scan dispatch (launch + 2 dependency bubbles).
//   bsum is only 49 ints: scatter and fused compute the exclusive prefix scan
//   themselves (wave 0: 49 L2-hot loads + 6 shuffle steps -> LDS bscan[64],
//   before their existing first barrier). col_un pad-zero moved to scan1_norm
//   block 0. Dispatch count 9 -> 8. Everything else r25/r20-exact (286.4/285.7 us).
// CLOSED axes (evidence): fused gather structure (7 perturbations, r9-r24),
//   launch_bounds(256,4) (6 spills r21, 8 starves r9), atomic-free dst CSR
//   (r14/r17 correctness), scatter depth (r22 noise).
// REQUIRES nb = ceil(N/1024) <= 64 (N <= 65536; here 50000 -> nb=49).

#define TPB 256
#define NBANK 8
#define GM 16
#define APAD 136  // 128+8 shorts: 272 B row stride
#define NREP 8    // dst degree-counter replicas
#define CHUNK 512 // LDS descriptor chunk (avg block needs ~160)
#define HSZ 12500 // src-histogram stripe size (50 KB LDS of int counters)
#define HB 32     // blocks per stripe

typedef __attribute__((ext_vector_type(8))) short bf16x8;
typedef __attribute__((ext_vector_type(4))) float f32x4;

__device__ inline unsigned short f2bf(float f) {
    unsigned int u = __builtin_bit_cast(unsigned int, f);
    u += 0x7fff + ((u >> 16) & 1);          // RNE
    return (unsigned short)(u >> 16);
}
__device__ inline float bf2f(unsigned short b) {
    unsigned int u = ((unsigned int)b) << 16;
    return __builtin_bit_cast(float, u);
}

// ---------------- prep1: src-hist (LDS) | dst degree+rank (atomic) | embed+weights ----------------
__global__ void prep1(const int* __restrict__ node_ids, const float* __restrict__ emb,
                      unsigned short* __restrict__ x, int n32,
                      const float* __restrict__ Ws, const float* __restrict__ Rws,
                      unsigned short* __restrict__ Wt, unsigned short* __restrict__ Rwt,
                      int wtotal,
                      const int* __restrict__ src, const int* __restrict__ dst,
                      unsigned short* __restrict__ out_part,
                      int* __restrict__ deg_rep, int* __restrict__ rank,
                      int E, int N, int histBlocks, int degBlocks) {
    __shared__ int cnt[HSZ];
    if ((int)blockIdx.x < histBlocks) {
        // ---- src out-degree striped histogram (LDS only) ----
        int t = threadIdx.x;
        int s = blockIdx.x >> 5;          // HB == 32
        int b = blockIdx.x & (HB - 1);
        int base = s * HSZ;
        for (int j = t; j < HSZ; j += TPB) cnt[j] = 0;
        __syncthreads();
        int per = (E + HB - 1) / HB;
        int lo = b * per;
        int hi = lo + per < E ? lo + per : E;
        for (int i = lo + t; i < hi; i += TPB) {
            int v = src[i] - base;
            if ((unsigned)v < (unsigned)HSZ) atomicAdd(&cnt[v], 1);
        }
        __syncthreads();
        for (int j = t; j < HSZ; j += TPB)
            out_part[(size_t)blockIdx.x * HSZ + j] = (unsigned short)cnt[j];
    } else if ((int)blockIdx.x < histBlocks + degBlocks) {
        int blk = blockIdx.x - histBlocks;
        int rep = blk & (NREP - 1);
        int* dd = deg_rep + (size_t)rep * N;     // dst counters (replica)
        int T = degBlocks * 256;
        int t0 = blk * 256 + threadIdx.x;
        int idx[4], dv[4];
        #pragma unroll
        for (int k = 0; k < 4; k++) {
            int i = t0 + k * T;
            idx[k] = (i < E) ? i : 0;
        }
        #pragma unroll
        for (int k = 0; k < 4; k++) dv[k] = dst[idx[k]];
        int r[4];
        #pragma unroll
        for (int k = 0; k < 4; k++)
            r[k] = (t0 + k * T < E) ? atomicAdd(&dd[dv[k]], 1) : 0;
        #pragma unroll
        for (int k = 0; k < 4; k++)
            if (t0 + k * T < E) rank[t0 + k * T] = r[k] | (rep << 24);
    } else {
        int gid = (blockIdx.x - histBlocks - degBlocks) * 256 + threadIdx.x;
        if (gid < n32) {
            int v = gid >> 5, c4 = gid & 31;
            int id = node_ids[v];
            float4 e = *(const float4*)&emb[id * 128 + c4 * 4];
            ushort4 o;
            o.x = f2bf(e.x); o.y = f2bf(e.y); o.z = f2bf(e.z); o.w = f2bf(e.w);
            *(ushort4*)&x[(size_t)v * 128 + c4 * 4] = o;
        }
        if (gid < wtotal) {
            int l = gid >> 14, rr = (gid >> 7) & 127, k = gid & 127;
            int sidx = l * 16384 + k * 128 + rr;
            Wt[gid]  = f2bf(Ws[sidx]);
            Rwt[gid] = f2bf(Rws[sidx]);
        }
    }
}

// sum dst replicas -> in_norm; sum src histogram partials -> out_norm;
// block-local exclusive scan of in-degree into row_ptr; replica slots rewritten to
// (replica prefix + row_ptr_local) so scatter needs one random read per edge.
// Block 0 zeroes the col_un pad (was boff_scan's job).
__global__ void scan1_norm(int* __restrict__ deg_rep,
                           const unsigned short* __restrict__ out_part,
                           float* __restrict__ out_norm, float* __restrict__ in_norm,
                           int* __restrict__ row_ptr, int* __restrict__ bsum, int n,
                           int2* __restrict__ col_un_pad) {
    __shared__ int tmp[1024];
    int t = threadIdx.x;
    if (blockIdx.x == 0 && t < 8) { int2 z; z.x = 0; z.y = 0; col_un_pad[t] = z; }
    int i = blockIdx.x * 1024 + t;
    int v = 0;
    int pref[NREP];
    if (i < n) {
        int run = 0;
        #pragma unroll
        for (int r = 0; r < NREP; r++) {
            int c = deg_rep[(size_t)r * n + i];
            pref[r] = run;
            run += c;
        }
        v = run;
        int s = i / HSZ;
        int li = i - s * HSZ;
        const unsigned short* op = out_part + ((size_t)s * HB) * HSZ + li;
        int dsv = 0;
        #pragma unroll 8
        for (int r = 0; r < HB; r++) dsv += op[(size_t)r * HSZ];
        out_norm[i] = dsv > 0 ? rsqrtf((float)dsv) : 0.f;
        in_norm[i]  = v   > 0 ? rsqrtf((float)v)   : 0.f;
    }
    tmp[t] = v;
    __syncthreads();
    for (int off = 1; off < 1024; off <<= 1) {
        int add = (t >= off) ? tmp[t - off] : 0;
        __syncthreads();
        tmp[t] += add;
        __syncthreads();
    }
    int ex = tmp[t] - v;                   // block-local exclusive scan
    if (i < n) {
        row_ptr[i] = ex;
        #pragma unroll
        for (int r = 0; r < NREP; r++)
            deg_rep[(size_t)r * n + i] = pref[r] + ex;   // prefix + row_ptr folded
    }
    if (t == 1023) bsum[blockIdx.x] = tmp[1023];
}

// in-wave exclusive scan of bsum (nb <= 64) into LDS; call from wave 0 (tid < 64)
__device__ inline void bsum_scan_wave0(const int* __restrict__ bsum, int nb,
                                       int* __restrict__ bscan, int tid) {
    int orig = (tid < nb) ? bsum[tid] : 0;
    int v = orig;
    #pragma unroll
    for (int off = 1; off < 64; off <<= 1) {
        int u = __shfl_up(v, off);
        if (tid >= off) v += u;
    }
    bscan[tid] = v - orig;
}

// atomic-free CSR fill with packed (src, out_norm[src]) descriptors; 4 edges/thread.
// pos = bscan[tile] + (replica prefix + row_ptr_local)[dv] + local rank.
// bscan computed in-kernel from bsum (boff_scan dispatch deleted, r26).
__global__ void scatter_kernel(const int* __restrict__ src, const int* __restrict__ dst,
                               const int* __restrict__ bsum, int nb,
                               const int* __restrict__ rank,
                               const float* __restrict__ out_norm,
                               const int* __restrict__ deg_rep,
                               int2* __restrict__ col_un, int E, int N, int T) {
    __shared__ int bscan[64];
    int tid = threadIdx.x;
    if (tid < 64) bsum_scan_wave0(bsum, nb, bscan, tid);
    __syncthreads();
    int t0 = blockIdx.x * blockDim.x + tid;
    int idx[4], sv[4], dv[4], rk[4];
    #pragma unroll
    for (int k = 0; k < 4; k++) {
        int i = t0 + k * T;
        idx[k] = (i < E) ? i : 0;
    }
    #pragma unroll
    for (int k = 0; k < 4; k++) { sv[k] = src[idx[k]]; dv[k] = dst[idx[k]]; rk[k] = rank[idx[k]]; }
    int pos[4]; float nm[4];
    #pragma unroll
    for (int k = 0; k < 4; k++) {
        int rep = ((unsigned)rk[k]) >> 24;
        int lr = rk[k] & 0xFFFFFF;
        pos[k] = bscan[dv[k] >> 10] + deg_rep[(size_t)rep * N + dv[k]] + lr;
        nm[k] = out_norm[sv[k]];
    }
    #pragma unroll
    for (int k = 0; k < 4; k++) {
        if (t0 + k * T < E) {
            int2 v; v.x = sv[k]; v.y = __float_as_int(nm[k]);
            col_un[pos[k]] = v;
        }
    }
}

// ---------------- fused per-layer kernel ----------------
// r8-optimum gather core + prev-layer BN affine folded in.
//   FIRST: r12-exact staging/finalize; accumulates layer-invariant nsum, writes once.
//   !FIRST: reads nsum[gnode]; staging applies x_hat=sc*h+sh; finalize
//           agg = inv*(sc*acc + sh*nsum). BF16OUT: raw h -> bf16 hb; else fp32 h.
//   bscan computed in-kernel from bsum (r26). INVARIANT: in != out (ping-pong).
// launch_bounds(256,4): CLOSED optimum — (256,6) spilled (r21), (256,8) starved (r9).
template<bool FIRST, bool BF16OUT>
__global__ __launch_bounds__(256, 4) void fused_layer_kernel(
    const unsigned short* __restrict__ x,
    const int* __restrict__ row_ptr, const int* __restrict__ bsumg, int nb,
    const int2* __restrict__ col_un,
    const float* __restrict__ in_norm,
    const unsigned short* __restrict__ Wt, const unsigned short* __restrict__ Rwt,
    const float* __restrict__ bvec, const float* __restrict__ Rbvec,
    const float* __restrict__ prevStats, const float* __restrict__ prevGamma,
    const float* __restrict__ prevBeta, float nrowsf,
    float* __restrict__ nsum,
    float* __restrict__ h, unsigned short* __restrict__ hb,
    float* __restrict__ stats, int nrows, int Etot) {
    __shared__ unsigned short As[GM * APAD];
    __shared__ unsigned short Xs[GM * APAD];
    __shared__ int2 Ld[CHUNK];
    __shared__ float bsum[128], bss[128];
    __shared__ float ssc[FIRST ? 4 : 128], ssh[FIRST ? 4 : 128];
    __shared__ int bscan[64];
    int tid = threadIdx.x;
    int m0 = blockIdx.x * GM;
    if (tid < 64) bsum_scan_wave0(bsumg, nb, bscan, tid);
    if (tid < 128) {
        bsum[tid] = 0.f; bss[tid] = 0.f;
        if constexpr (!FIRST) {
            float s = 0.f, sq = 0.f;
            #pragma unroll
            for (int b2 = 0; b2 < NBANK; b2++) {
                s  += prevStats[b2 * 256 + tid];
                sq += prevStats[b2 * 256 + tid + 128];
            }
            float mu = s / nrowsf;
            float var = sq / nrowsf - mu * mu;
            float rstd = rsqrtf(var + 1e-5f);
            float sc = prevGamma[tid] * rstd;
            ssc[tid] = sc;
            ssh[tid] = prevBeta[tid] - sc * mu;
        }
    }
    __syncthreads();   // bscan, ssc/ssh (and bsum/bss) visible

    // ---- gather ----
    {
        int node = tid >> 4;
        int part = tid & 15;
        int gnode = m0 + node;
        if (gnode >= nrows) gnode = nrows - 1;
        // stage own row chunk for residual GEMM
        uint4 xv = *(const uint4*)&x[(size_t)gnode * 128 + part * 8];
        if constexpr (FIRST) {
            *(uint4*)&Xs[node * APAD + part * 8] = xv;
        } else {
            const unsigned short* xs = (const unsigned short*)&xv;
            uint4 pk;
            pk.x = (unsigned int)f2bf(ssc[part * 8 + 0] * bf2f(xs[0]) + ssh[part * 8 + 0])
                 | ((unsigned int)f2bf(ssc[part * 8 + 1] * bf2f(xs[1]) + ssh[part * 8 + 1]) << 16);
            pk.y = (unsigned int)f2bf(ssc[part * 8 + 2] * bf2f(xs[2]) + ssh[part * 8 + 2])
                 | ((unsigned int)f2bf(ssc[part * 8 + 3] * bf2f(xs[3]) + ssh[part * 8 + 3]) << 16);
            pk.z = (unsigned int)f2bf(ssc[part * 8 + 4] * bf2f(xs[4]) + ssh[part * 8 + 4])
                 | ((unsigned int)f2bf(ssc[part * 8 + 5] * bf2f(xs[5]) + ssh[part * 8 + 5]) << 16);
            pk.w = (unsigned int)f2bf(ssc[part * 8 + 6] * bf2f(xs[6]) + ssh[part * 8 + 6])
                 | ((unsigned int)f2bf(ssc[part * 8 + 7] * bf2f(xs[7]) + ssh[part * 8 + 7]) << 16);
            *(uint4*)&Xs[node * APAD + part * 8] = pk;
        }
        float inv = in_norm[gnode];
        float nsumv = 0.f;
        if constexpr (!FIRST) nsumv = nsum[gnode];
        int beg = row_ptr[gnode] + bscan[gnode >> 10];
        int end = (gnode == nrows - 1) ? Etot
                                       : row_ptr[gnode + 1] + bscan[(gnode + 1) >> 10];
        // block's contiguous descriptor range
        int blkBeg = row_ptr[m0] + bscan[m0 >> 10];
        int lastN = m0 + GM;
        int blkEnd = (lastN >= nrows) ? Etot : row_ptr[lastN] + bscan[lastN >> 10];

        float acc[8];
        #pragma unroll
        for (int j = 0; j < 8; j++) acc[j] = 0.f;
        const unsigned short* xb = x + part * 8;

        for (int chunk = blkBeg; chunk < blkEnd; chunk += CHUNK) {
            int chunkEnd = chunk + CHUNK < blkEnd ? chunk + CHUNK : blkEnd;
            int nd = chunkEnd - chunk;
            __syncthreads();   // previous chunk fully consumed
            for (int i = tid; i < nd; i += TPB) Ld[i] = col_un[chunk + i];
            __syncthreads();
            int e0 = beg > chunk ? beg : chunk;
            int e1 = end < chunkEnd ? end : chunkEnd;
            for (int e = e0; e < e1; e += 8) {
                int rem = e1 - e;
                int base = e - chunk;
                int2 ed[8];
                #pragma unroll
                for (int j = 0; j < 8; j++)
                    ed[j] = Ld[(j < rem) ? (base + j) : base];
                uint4 q[8];
                #pragma unroll
                for (int j = 0; j < 8; j++)
                    q[j] = *(const uint4*)(xb + (size_t)(unsigned)ed[j].x * 128);
                #pragma unroll
                for (int j = 0; j < 8; j++) {
                    float nn = (j < rem) ? __int_as_float(ed[j].y) : 0.f;
                    if constexpr (FIRST) nsumv += nn;
                    const unsigned int* w = (const unsigned int*)&q[j];
                    #pragma unroll
                    for (int t = 0; t < 4; t++) {
                        acc[2 * t]     += nn * bf2f((unsigned short)w[t]);
                        acc[2 * t + 1] += nn * bf2f((unsigned short)(w[t] >> 16));
                    }
                }
            }
        }
        if constexpr (FIRST) {
            if (part == 0) nsum[gnode] = nsumv;
            #pragma unroll
            for (int j = 0; j < 8; j++) acc[j] *= inv;
        } else {
            // prev-BN affine on aggregate: sum nn*(sc*h+sh) = sc*acc + sh*nsum
            #pragma unroll
            for (int j = 0; j < 8; j++)
                acc[j] = (ssc[part * 8 + j] * acc[j] + ssh[part * 8 + j] * nsumv) * inv;
        }
        uint4 pk;
        pk.x = (unsigned int)f2bf(acc[0]) | ((unsigned int)f2bf(acc[1]) << 16);
        pk.y = (unsigned int)f2bf(acc[2]) | ((unsigned int)f2bf(acc[3]) << 16);
        pk.z = (unsigned int)f2bf(acc[4]) | ((unsigned int)f2bf(acc[5]) << 16);
        pk.w = (unsigned int)f2bf(acc[6]) | ((unsigned int)f2bf(acc[7]) << 16);
        *(uint4*)&As[node * APAD + part * 8] = pk;
    }
    __syncthreads();

    // ---- dual GEMM via MFMA 16x16x32 bf16 ----
    int wave = tid >> 6;
    int lane = tid & 63;
    int m = lane & 15;
    int quad = lane >> 4;

    f32x4 accA[2], accX[2];
    #pragma unroll
    for (int t = 0; t < 2; t++) { accA[t] = (f32x4){0,0,0,0}; accX[t] = (f32x4){0,0,0,0}; }

    #pragma unroll
    for (int kc = 0; kc < 4; kc++) {
        int koff = kc * 32 + quad * 8;
        bf16x8 aA = *(const bf16x8*)&As[m * APAD + koff];
        bf16x8 aX = *(const bf16x8*)&Xs[m * APAD + koff];
        #pragma unroll
        for (int t = 0; t < 2; t++) {
            int nrow = (wave * 2 + t) * 16 + m;
            bf16x8 bW = *(const bf16x8*)&Wt[(size_t)nrow * 128 + koff];
            bf16x8 bR = *(const bf16x8*)&Rwt[(size_t)nrow * 128 + koff];
            accA[t] = __builtin_amdgcn_mfma_f32_16x16x32_bf16(aA, bW, accA[t], 0, 0, 0);
            accX[t] = __builtin_amdgcn_mfma_f32_16x16x32_bf16(aX, bR, accX[t], 0, 0, 0);
        }
    }

    // ---- epilogue ----
    #pragma unroll
    for (int t = 0; t < 2; t++) {
        int col = (wave * 2 + t) * 16 + m;
        float bW = bvec[col], bR = Rbvec[col];
        float cs = 0.f, cq = 0.f;
        #pragma unroll
        for (int reg = 0; reg < 4; reg++) {
            int gr = m0 + quad * 4 + reg;
            float hA = accA[t][reg] + bW; hA = hA > 0.f ? hA : 0.f;
            float hX = accX[t][reg] + bR; hX = hX > 0.f ? hX : 0.f;
            float v = hA + hX;
            if (gr < nrows) {
                if constexpr (BF16OUT) hb[(size_t)gr * 128 + col] = f2bf(v);
                else                   h[(size_t)gr * 128 + col] = v;
            } else {
                v = 0.f;
            }
            cs += v; cq += v * v;
        }
        cs += __shfl_xor(cs, 16); cs += __shfl_xor(cs, 32);
        cq += __shfl_xor(cq, 16); cq += __shfl_xor(cq, 32);
        if (lane < 16) {
            atomicAdd(&bsum[col], cs);
            atomicAdd(&bss[col], cq);
        }
    }
    __syncthreads();
    if (tid < 128) {
        float* sb = stats + (size_t)(blockIdx.x & (NBANK - 1)) * 256;
        atomicAdd(&sb[tid], bsum[tid]);
        atomicAdd(&sb[tid + 128], bss[tid]);
    }
}

// ---------------- final BN apply (fp32 out) ----------------
__global__ void norm_apply_f32(const float* __restrict__ h, const float* __restrict__ stats,
                               const float* __restrict__ gamma, const float* __restrict__ beta,
                               float* __restrict__ dstp, int total4, float n) {
    __shared__ float ssc[128], ssh[128];
    int t = threadIdx.x;
    if (t < 128) {
        float s = 0.f, sq = 0.f;
        #pragma unroll
        for (int b2 = 0; b2 < NBANK; b2++) {
            s  += stats[b2 * 256 + t];
            sq += stats[b2 * 256 + t + 128];
        }
        float mu = s / n;
        float var = sq / n - mu * mu;
        float rstd = rsqrtf(var + 1e-5f);
        float sc = gamma[t] * rstd;
        ssc[t] = sc;
        ssh[t] = beta[t] - sc * mu;
    }
    __syncthreads();
    int gid = blockIdx.x * blockDim.x + t;
    if (gid >= total4) return;
    int c4 = gid & 31;
    float4 sc = *(const float4*)&ssc[c4 * 4];
    float4 sh = *(const float4*)&ssh[c4 * 4];
    float4 v = ((const float4*)h)[gid];
    float4 o;
    o.x = sc.x * v.x + sh.x;
    o.y = sc.y * v.y + sh.y;
    o.z = sc.z * v.z + sh.z;
    o.w = sc.w * v.w + sh.w;
    ((float4*)dstp)[gid] = o;
}

// ---------------- launch ----------------

extern "C" void kernel_launch(void* const* d_in, const int* in_sizes, int n_in,
                              void* d_out, int out_size, void* d_ws, size_t ws_size,
                              hipStream_t stream) {
    const int*   node_ids = (const int*)d_in[0];
    const int*   src      = (const int*)d_in[1];
    const int*   dst      = (const int*)d_in[2];
    const float* emb      = (const float*)d_in[3];
    const float* Ws       = (const float*)d_in[4];
    const float* bs       = (const float*)d_in[5];
    const float* Rws      = (const float*)d_in[6];
    const float* Rbs      = (const float*)d_in[7];
    const float* gammas   = (const float*)d_in[8];
    const float* betas    = (const float*)d_in[9];

    const int N = in_sizes[0];
    const int E = in_sizes[1];
    const int D = 128;
    const int L = in_sizes[4] / (D * D);

    size_t off = 0;
    auto alloc = [&](size_t bytes) -> void* {
        void* p = (char*)d_ws + off;
        off += (bytes + 255) & ~(size_t)255;
        return p;
    };
    int NS = (N + HSZ - 1) / HSZ;
    int*   deg_rep  = (int*)alloc((size_t)NREP * N * 4);
    unsigned short* out_part = (unsigned short*)alloc((size_t)NS * HB * HSZ * 2);
    int*   rank     = (int*)alloc((size_t)E * 4);
    float* out_norm = (float*)alloc((size_t)N * 4);
    float* in_norm  = (float*)alloc((size_t)N * 4);
    float* nsum     = (float*)alloc((size_t)N * 4);
    int*   row_ptr  = (int*)alloc((size_t)(N + 1) * 4);
    int*   bsumg    = (int*)alloc(64 * 4);
    int2*  col_un   = (int2*)alloc(((size_t)E + 8) * 8);
    float* stats    = (float*)alloc((size_t)L * NBANK * 256 * 4);
    unsigned short* Wt   = (unsigned short*)alloc((size_t)L * D * D * 2);
    unsigned short* Rwt  = (unsigned short*)alloc((size_t)L * D * D * 2);
    unsigned short* x    = (unsigned short*)alloc((size_t)N * D * 2);
    unsigned short* hb0  = (unsigned short*)alloc((size_t)N * D * 2);
    unsigned short* hb1  = (unsigned short*)alloc((size_t)N * D * 2);
    float* h = (float*)d_out;  // fp32 h scratch == output buffer (last layer only)

    hipMemsetAsync(deg_rep, 0, (size_t)NREP * N * 4, stream);
    hipMemsetAsync(stats, 0, (size_t)L * NBANK * 256 * 4, stream);

    // merged prep: src hist | dst degree+rank | emb + weights
    int histBlocks = NS * HB;                       // 128
    int degBlocks = (E + 1023) / 1024;              // 4 edges/thread
    int n32 = N * 32, wtotal = L * D * D;
    int embBlocks = (n32 + TPB - 1) / TPB;
    prep1<<<histBlocks + degBlocks + embBlocks, TPB, 0, stream>>>(
        node_ids, emb, x, n32, Ws, Rws, Wt, Rwt, wtotal,
        src, dst, out_part, deg_rep, rank, E, N, histBlocks, degBlocks);

    int nb = (N + 1023) / 1024;
    scan1_norm<<<nb, 1024, 0, stream>>>(deg_rep, out_part, out_norm, in_norm, row_ptr,
                                        bsumg, N, col_un + E);
    int scatBlocks = (E + 1023) / 1024;
    scatter_kernel<<<scatBlocks, TPB, 0, stream>>>(src, dst, bsumg, nb, rank, out_norm,
                                                   deg_rep, col_un, E, N, scatBlocks * 256);

    int gblocks = (N + GM - 1) / GM;
    // ping-pong buffers: layer 0 x->hb0, layer 1 hb0->hb1, layer 2 hb1->fp32 h
    for (int l = 0; l < L; l++) {
        const unsigned short* Wtl  = Wt  + (size_t)l * D * D;
        const unsigned short* Rwtl = Rwt + (size_t)l * D * D;
        const float* b   = bs  + (size_t)l * D;
        const float* Rb  = Rbs + (size_t)l * D;
        float* st = stats + (size_t)l * NBANK * 256;

        const unsigned short* xin = (l == 0) ? x : ((l & 1) ? hb0 : hb1);
        unsigned short* hbOut = (l < L - 1) ? (((l & 1) == 0) ? hb0 : hb1) : nullptr;
        const float* pst = (l == 0) ? nullptr : stats + (size_t)(l - 1) * NBANK * 256;
        const float* pgm = (l == 0) ? nullptr : gammas + (size_t)(l - 1) * D;
        const float* pbt = (l == 0) ? nullptr : betas  + (size_t)(l - 1) * D;

        if (l == 0) {
            fused_layer_kernel<true, true><<<gblocks, TPB, 0, stream>>>(
                xin, row_ptr, bsumg, nb, col_un, in_norm, Wtl, Rwtl, b, Rb,
                nullptr, nullptr, nullptr, (float)N, nsum, h, hbOut, st, N, E);
        } else if (l < L - 1) {
            fused_layer_kernel<false, true><<<gblocks, TPB, 0, stream>>>(
                xin, row_ptr, bsumg, nb, col_un, in_norm, Wtl, Rwtl, b, Rb,
                pst, pgm, pbt, (float)N, nsum, h, hbOut, st, N, E);
        } else {
            fused_layer_kernel<false, false><<<gblocks, TPB, 0, stream>>>(
                xin, row_ptr, bsumg, nb, col_un, in_norm, Wtl, Rwtl, b, Rb,
                pst, pgm, pbt, (float)N, nsum, h, hbOut, st, N, E);
        }
    }
    // final BN apply on fp32 h (in d_out) -> d_out
    norm_apply_f32<<<(N * 32 + TPB - 1) / TPB, TPB, 0, stream>>>(
        h, stats + (size_t)(L - 1) * NBANK * 256,
        gammas + (size_t)(L - 1) * D, betas + (size_t)(L - 1) * D,
        (float*)d_out, N * 32, (float)N);
}

// Round 16
// 283.870 us; speedup vs baseline: 1.0232x; 1.0232x over previous
//
#include <hip/hip_runtime.h>
#include <hip/hip_bf16.h>

// GCN node encoder: 3 layers GraphConv(norm=both) + residual linear + ReLU + BatchNorm.
// N=50000, E=500000, D=128, L=3.
// Round 27: r26 post-mortem — in-kernel bscan in FUSED cost ~2us/layer (3125 blk x 3
// layers re-deriving a 49-int scan; LDS 14848->15360). Hybrid fix:
//   - scatter keeps its in-kernel bscan AND block 0 writes it to global boff
//   - fused reverts to r25-exact boff-reading form (best measured: 286.4/285.7)
//   - boff_scan dispatch stays deleted (8 dispatches)
// CLOSED axes (evidence): fused gather structure (r9-r24, 7 perturbations),
// launch_bounds(256,4) (r21 spills, r9 starves), atomic-free dst CSR (r14/r17),
// scatter depth (r22), in-fused bscan (r26).

#define TPB 256
#define NBANK 8
#define GM 16
#define APAD 136  // 128+8 shorts: 272 B row stride
#define NREP 8    // dst degree-counter replicas
#define CHUNK 512 // LDS descriptor chunk (avg block needs ~160)
#define HSZ 12500 // src-histogram stripe size (50 KB LDS of int counters)
#define HB 32     // blocks per stripe

typedef __attribute__((ext_vector_type(8))) short bf16x8;
typedef __attribute__((ext_vector_type(4))) float f32x4;

__device__ inline unsigned short f2bf(float f) {
    unsigned int u = __builtin_bit_cast(unsigned int, f);
    u += 0x7fff + ((u >> 16) & 1);          // RNE
    return (unsigned short)(u >> 16);
}
__device__ inline float bf2f(unsigned short b) {
    unsigned int u = ((unsigned int)b) << 16;
    return __builtin_bit_cast(float, u);
}

// ---------------- prep1: src-hist (LDS) | dst degree+rank (atomic) | embed+weights ----------------
__global__ void prep1(const int* __restrict__ node_ids, const float* __restrict__ emb,
                      unsigned short* __restrict__ x, int n32,
                      const float* __restrict__ Ws, const float* __restrict__ Rws,
                      unsigned short* __restrict__ Wt, unsigned short* __restrict__ Rwt,
                      int wtotal,
                      const int* __restrict__ src, const int* __restrict__ dst,
                      unsigned short* __restrict__ out_part,
                      int* __restrict__ deg_rep, int* __restrict__ rank,
                      int E, int N, int histBlocks, int degBlocks) {
    __shared__ int cnt[HSZ];
    if ((int)blockIdx.x < histBlocks) {
        // ---- src out-degree striped histogram (LDS only) ----
        int t = threadIdx.x;
        int s = blockIdx.x >> 5;          // HB == 32
        int b = blockIdx.x & (HB - 1);
        int base = s * HSZ;
        for (int j = t; j < HSZ; j += TPB) cnt[j] = 0;
        __syncthreads();
        int per = (E + HB - 1) / HB;
        int lo = b * per;
        int hi = lo + per < E ? lo + per : E;
        for (int i = lo + t; i < hi; i += TPB) {
            int v = src[i] - base;
            if ((unsigned)v < (unsigned)HSZ) atomicAdd(&cnt[v], 1);
        }
        __syncthreads();
        for (int j = t; j < HSZ; j += TPB)
            out_part[(size_t)blockIdx.x * HSZ + j] = (unsigned short)cnt[j];
    } else if ((int)blockIdx.x < histBlocks + degBlocks) {
        int blk = blockIdx.x - histBlocks;
        int rep = blk & (NREP - 1);
        int* dd = deg_rep + (size_t)rep * N;     // dst counters (replica)
        int T = degBlocks * 256;
        int t0 = blk * 256 + threadIdx.x;
        int idx[4], dv[4];
        #pragma unroll
        for (int k = 0; k < 4; k++) {
            int i = t0 + k * T;
            idx[k] = (i < E) ? i : 0;
        }
        #pragma unroll
        for (int k = 0; k < 4; k++) dv[k] = dst[idx[k]];
        int r[4];
        #pragma unroll
        for (int k = 0; k < 4; k++)
            r[k] = (t0 + k * T < E) ? atomicAdd(&dd[dv[k]], 1) : 0;
        #pragma unroll
        for (int k = 0; k < 4; k++)
            if (t0 + k * T < E) rank[t0 + k * T] = r[k] | (rep << 24);
    } else {
        int gid = (blockIdx.x - histBlocks - degBlocks) * 256 + threadIdx.x;
        if (gid < n32) {
            int v = gid >> 5, c4 = gid & 31;
            int id = node_ids[v];
            float4 e = *(const float4*)&emb[id * 128 + c4 * 4];
            ushort4 o;
            o.x = f2bf(e.x); o.y = f2bf(e.y); o.z = f2bf(e.z); o.w = f2bf(e.w);
            *(ushort4*)&x[(size_t)v * 128 + c4 * 4] = o;
        }
        if (gid < wtotal) {
            int l = gid >> 14, rr = (gid >> 7) & 127, k = gid & 127;
            int sidx = l * 16384 + k * 128 + rr;
            Wt[gid]  = f2bf(Ws[sidx]);
            Rwt[gid] = f2bf(Rws[sidx]);
        }
    }
}

// sum dst replicas -> in_norm; sum src histogram partials -> out_norm;
// block-local exclusive scan of in-degree into row_ptr; replica slots rewritten to
// (replica prefix + row_ptr_local) so scatter needs one random read per edge.
// Block 0 zeroes the col_un pad.
__global__ void scan1_norm(int* __restrict__ deg_rep,
                           const unsigned short* __restrict__ out_part,
                           float* __restrict__ out_norm, float* __restrict__ in_norm,
                           int* __restrict__ row_ptr, int* __restrict__ bsum, int n,
                           int2* __restrict__ col_un_pad) {
    __shared__ int tmp[1024];
    int t = threadIdx.x;
    if (blockIdx.x == 0 && t < 8) { int2 z; z.x = 0; z.y = 0; col_un_pad[t] = z; }
    int i = blockIdx.x * 1024 + t;
    int v = 0;
    int pref[NREP];
    if (i < n) {
        int run = 0;
        #pragma unroll
        for (int r = 0; r < NREP; r++) {
            int c = deg_rep[(size_t)r * n + i];
            pref[r] = run;
            run += c;
        }
        v = run;
        int s = i / HSZ;
        int li = i - s * HSZ;
        const unsigned short* op = out_part + ((size_t)s * HB) * HSZ + li;
        int dsv = 0;
        #pragma unroll 8
        for (int r = 0; r < HB; r++) dsv += op[(size_t)r * HSZ];
        out_norm[i] = dsv > 0 ? rsqrtf((float)dsv) : 0.f;
        in_norm[i]  = v   > 0 ? rsqrtf((float)v)   : 0.f;
    }
    tmp[t] = v;
    __syncthreads();
    for (int off = 1; off < 1024; off <<= 1) {
        int add = (t >= off) ? tmp[t - off] : 0;
        __syncthreads();
        tmp[t] += add;
        __syncthreads();
    }
    int ex = tmp[t] - v;                   // block-local exclusive scan
    if (i < n) {
        row_ptr[i] = ex;
        #pragma unroll
        for (int r = 0; r < NREP; r++)
            deg_rep[(size_t)r * n + i] = pref[r] + ex;   // prefix + row_ptr folded
    }
    if (t == 1023) bsum[blockIdx.x] = tmp[1023];
}

// atomic-free CSR fill with packed (src, out_norm[src]) descriptors; 4 edges/thread.
// Computes bscan in-kernel from bsum (wave 0); block 0 ALSO writes it to global boff
// for the fused layers (boff_scan dispatch deleted — r27 hybrid).
__global__ void scatter_kernel(const int* __restrict__ src, const int* __restrict__ dst,
                               const int* __restrict__ bsum, int nb,
                               int* __restrict__ boff,
                               const int* __restrict__ rank,
                               const float* __restrict__ out_norm,
                               const int* __restrict__ deg_rep,
                               int2* __restrict__ col_un, int E, int N, int T) {
    __shared__ int bscan[64];
    int tid = threadIdx.x;
    if (tid < 64) {
        int orig = (tid < nb) ? bsum[tid] : 0;
        int v = orig;
        #pragma unroll
        for (int off = 1; off < 64; off <<= 1) {
            int u = __shfl_up(v, off);
            if (tid >= off) v += u;
        }
        bscan[tid] = v - orig;
        if (blockIdx.x == 0) boff[tid] = v - orig;   // publish for fused layers
    }
    __syncthreads();
    int t0 = blockIdx.x * blockDim.x + tid;
    int idx[4], sv[4], dv[4], rk[4];
    #pragma unroll
    for (int k = 0; k < 4; k++) {
        int i = t0 + k * T;
        idx[k] = (i < E) ? i : 0;
    }
    #pragma unroll
    for (int k = 0; k < 4; k++) { sv[k] = src[idx[k]]; dv[k] = dst[idx[k]]; rk[k] = rank[idx[k]]; }
    int pos[4]; float nm[4];
    #pragma unroll
    for (int k = 0; k < 4; k++) {
        int rep = ((unsigned)rk[k]) >> 24;
        int lr = rk[k] & 0xFFFFFF;
        pos[k] = bscan[dv[k] >> 10] + deg_rep[(size_t)rep * N + dv[k]] + lr;
        nm[k] = out_norm[sv[k]];
    }
    #pragma unroll
    for (int k = 0; k < 4; k++) {
        if (t0 + k * T < E) {
            int2 v; v.x = sv[k]; v.y = __float_as_int(nm[k]);
            col_un[pos[k]] = v;
        }
    }
}

// ---------------- fused per-layer kernel (r25-exact: reads global boff) ----------------
// r8-optimum gather core + prev-layer BN affine folded in.
//   FIRST: r12-exact staging/finalize; accumulates layer-invariant nsum, writes once.
//   !FIRST: reads nsum[gnode]; staging applies x_hat=sc*h+sh; finalize
//           agg = inv*(sc*acc + sh*nsum). BF16OUT: raw h -> bf16 hb; else fp32 h.
//   INVARIANT: input buffer != output buffer (ping-pong).
// launch_bounds(256,4): CLOSED optimum — (256,6) spilled (r21), (256,8) starved (r9).
template<bool FIRST, bool BF16OUT>
__global__ __launch_bounds__(256, 4) void fused_layer_kernel(
    const unsigned short* __restrict__ x,
    const int* __restrict__ row_ptr, const int* __restrict__ boff,
    const int2* __restrict__ col_un,
    const float* __restrict__ in_norm,
    const unsigned short* __restrict__ Wt, const unsigned short* __restrict__ Rwt,
    const float* __restrict__ bvec, const float* __restrict__ Rbvec,
    const float* __restrict__ prevStats, const float* __restrict__ prevGamma,
    const float* __restrict__ prevBeta, float nrowsf,
    float* __restrict__ nsum,
    float* __restrict__ h, unsigned short* __restrict__ hb,
    float* __restrict__ stats, int nrows, int Etot) {
    __shared__ unsigned short As[GM * APAD];
    __shared__ unsigned short Xs[GM * APAD];
    __shared__ int2 Ld[CHUNK];
    __shared__ float bsum[128], bss[128];
    __shared__ float ssc[FIRST ? 4 : 128], ssh[FIRST ? 4 : 128];
    int tid = threadIdx.x;
    int m0 = blockIdx.x * GM;
    if (tid < 128) {
        bsum[tid] = 0.f; bss[tid] = 0.f;
        if constexpr (!FIRST) {
            float s = 0.f, sq = 0.f;
            #pragma unroll
            for (int b2 = 0; b2 < NBANK; b2++) {
                s  += prevStats[b2 * 256 + tid];
                sq += prevStats[b2 * 256 + tid + 128];
            }
            float mu = s / nrowsf;
            float var = sq / nrowsf - mu * mu;
            float rstd = rsqrtf(var + 1e-5f);
            float sc = prevGamma[tid] * rstd;
            ssc[tid] = sc;
            ssh[tid] = prevBeta[tid] - sc * mu;
        }
    }
    __syncthreads();   // ssc/ssh (and bsum/bss) visible

    // ---- gather ----
    {
        int node = tid >> 4;
        int part = tid & 15;
        int gnode = m0 + node;
        if (gnode >= nrows) gnode = nrows - 1;
        // stage own row chunk for residual GEMM
        uint4 xv = *(const uint4*)&x[(size_t)gnode * 128 + part * 8];
        if constexpr (FIRST) {
            *(uint4*)&Xs[node * APAD + part * 8] = xv;
        } else {
            const unsigned short* xs = (const unsigned short*)&xv;
            uint4 pk;
            pk.x = (unsigned int)f2bf(ssc[part * 8 + 0] * bf2f(xs[0]) + ssh[part * 8 + 0])
                 | ((unsigned int)f2bf(ssc[part * 8 + 1] * bf2f(xs[1]) + ssh[part * 8 + 1]) << 16);
            pk.y = (unsigned int)f2bf(ssc[part * 8 + 2] * bf2f(xs[2]) + ssh[part * 8 + 2])
                 | ((unsigned int)f2bf(ssc[part * 8 + 3] * bf2f(xs[3]) + ssh[part * 8 + 3]) << 16);
            pk.z = (unsigned int)f2bf(ssc[part * 8 + 4] * bf2f(xs[4]) + ssh[part * 8 + 4])
                 | ((unsigned int)f2bf(ssc[part * 8 + 5] * bf2f(xs[5]) + ssh[part * 8 + 5]) << 16);
            pk.w = (unsigned int)f2bf(ssc[part * 8 + 6] * bf2f(xs[6]) + ssh[part * 8 + 6])
                 | ((unsigned int)f2bf(ssc[part * 8 + 7] * bf2f(xs[7]) + ssh[part * 8 + 7]) << 16);
            *(uint4*)&Xs[node * APAD + part * 8] = pk;
        }
        float inv = in_norm[gnode];
        float nsumv = 0.f;
        if constexpr (!FIRST) nsumv = nsum[gnode];
        int beg = row_ptr[gnode] + boff[gnode >> 10];
        int end = (gnode == nrows - 1) ? Etot
                                       : row_ptr[gnode + 1] + boff[(gnode + 1) >> 10];
        // block's contiguous descriptor range
        int blkBeg = row_ptr[m0] + boff[m0 >> 10];
        int lastN = m0 + GM;
        int blkEnd = (lastN >= nrows) ? Etot : row_ptr[lastN] + boff[lastN >> 10];

        float acc[8];
        #pragma unroll
        for (int j = 0; j < 8; j++) acc[j] = 0.f;
        const unsigned short* xb = x + part * 8;

        for (int chunk = blkBeg; chunk < blkEnd; chunk += CHUNK) {
            int chunkEnd = chunk + CHUNK < blkEnd ? chunk + CHUNK : blkEnd;
            int nd = chunkEnd - chunk;
            __syncthreads();   // previous chunk fully consumed
            for (int i = tid; i < nd; i += TPB) Ld[i] = col_un[chunk + i];
            __syncthreads();
            int e0 = beg > chunk ? beg : chunk;
            int e1 = end < chunkEnd ? end : chunkEnd;
            for (int e = e0; e < e1; e += 8) {
                int rem = e1 - e;
                int base = e - chunk;
                int2 ed[8];
                #pragma unroll
                for (int j = 0; j < 8; j++)
                    ed[j] = Ld[(j < rem) ? (base + j) : base];
                uint4 q[8];
                #pragma unroll
                for (int j = 0; j < 8; j++)
                    q[j] = *(const uint4*)(xb + (size_t)(unsigned)ed[j].x * 128);
                #pragma unroll
                for (int j = 0; j < 8; j++) {
                    float nn = (j < rem) ? __int_as_float(ed[j].y) : 0.f;
                    if constexpr (FIRST) nsumv += nn;
                    const unsigned int* w = (const unsigned int*)&q[j];
                    #pragma unroll
                    for (int t = 0; t < 4; t++) {
                        acc[2 * t]     += nn * bf2f((unsigned short)w[t]);
                        acc[2 * t + 1] += nn * bf2f((unsigned short)(w[t] >> 16));
                    }
                }
            }
        }
        if constexpr (FIRST) {
            if (part == 0) nsum[gnode] = nsumv;
            #pragma unroll
            for (int j = 0; j < 8; j++) acc[j] *= inv;
        } else {
            // prev-BN affine on aggregate: sum nn*(sc*h+sh) = sc*acc + sh*nsum
            #pragma unroll
            for (int j = 0; j < 8; j++)
                acc[j] = (ssc[part * 8 + j] * acc[j] + ssh[part * 8 + j] * nsumv) * inv;
        }
        uint4 pk;
        pk.x = (unsigned int)f2bf(acc[0]) | ((unsigned int)f2bf(acc[1]) << 16);
        pk.y = (unsigned int)f2bf(acc[2]) | ((unsigned int)f2bf(acc[3]) << 16);
        pk.z = (unsigned int)f2bf(acc[4]) | ((unsigned int)f2bf(acc[5]) << 16);
        pk.w = (unsigned int)f2bf(acc[6]) | ((unsigned int)f2bf(acc[7]) << 16);
        *(uint4*)&As[node * APAD + part * 8] = pk;
    }
    __syncthreads();

    // ---- dual GEMM via MFMA 16x16x32 bf16 ----
    int wave = tid >> 6;
    int lane = tid & 63;
    int m = lane & 15;
    int quad = lane >> 4;

    f32x4 accA[2], accX[2];
    #pragma unroll
    for (int t = 0; t < 2; t++) { accA[t] = (f32x4){0,0,0,0}; accX[t] = (f32x4){0,0,0,0}; }

    #pragma unroll
    for (int kc = 0; kc < 4; kc++) {
        int koff = kc * 32 + quad * 8;
        bf16x8 aA = *(const bf16x8*)&As[m * APAD + koff];
        bf16x8 aX = *(const bf16x8*)&Xs[m * APAD + koff];
        #pragma unroll
        for (int t = 0; t < 2; t++) {
            int nrow = (wave * 2 + t) * 16 + m;
            bf16x8 bW = *(const bf16x8*)&Wt[(size_t)nrow * 128 + koff];
            bf16x8 bR = *(const bf16x8*)&Rwt[(size_t)nrow * 128 + koff];
            accA[t] = __builtin_amdgcn_mfma_f32_16x16x32_bf16(aA, bW, accA[t], 0, 0, 0);
            accX[t] = __builtin_amdgcn_mfma_f32_16x16x32_bf16(aX, bR, accX[t], 0, 0, 0);
        }
    }

    // ---- epilogue ----
    #pragma unroll
    for (int t = 0; t < 2; t++) {
        int col = (wave * 2 + t) * 16 + m;
        float bW = bvec[col], bR = Rbvec[col];
        float cs = 0.f, cq = 0.f;
        #pragma unroll
        for (int reg = 0; reg < 4; reg++) {
            int gr = m0 + quad * 4 + reg;
            float hA = accA[t][reg] + bW; hA = hA > 0.f ? hA : 0.f;
            float hX = accX[t][reg] + bR; hX = hX > 0.f ? hX : 0.f;
            float v = hA + hX;
            if (gr < nrows) {
                if constexpr (BF16OUT) hb[(size_t)gr * 128 + col] = f2bf(v);
                else                   h[(size_t)gr * 128 + col] = v;
            } else {
                v = 0.f;
            }
            cs += v; cq += v * v;
        }
        cs += __shfl_xor(cs, 16); cs += __shfl_xor(cs, 32);
        cq += __shfl_xor(cq, 16); cq += __shfl_xor(cq, 32);
        if (lane < 16) {
            atomicAdd(&bsum[col], cs);
            atomicAdd(&bss[col], cq);
        }
    }
    __syncthreads();
    if (tid < 128) {
        float* sb = stats + (size_t)(blockIdx.x & (NBANK - 1)) * 256;
        atomicAdd(&sb[tid], bsum[tid]);
        atomicAdd(&sb[tid + 128], bss[tid]);
    }
}

// ---------------- final BN apply (fp32 out) ----------------
__global__ void norm_apply_f32(const float* __restrict__ h, const float* __restrict__ stats,
                               const float* __restrict__ gamma, const float* __restrict__ beta,
                               float* __restrict__ dstp, int total4, float n) {
    __shared__ float ssc[128], ssh[128];
    int t = threadIdx.x;
    if (t < 128) {
        float s = 0.f, sq = 0.f;
        #pragma unroll
        for (int b2 = 0; b2 < NBANK; b2++) {
            s  += stats[b2 * 256 + t];
            sq += stats[b2 * 256 + t + 128];
        }
        float mu = s / n;
        float var = sq / n - mu * mu;
        float rstd = rsqrtf(var + 1e-5f);
        float sc = gamma[t] * rstd;
        ssc[t] = sc;
        ssh[t] = beta[t] - sc * mu;
    }
    __syncthreads();
    int gid = blockIdx.x * blockDim.x + t;
    if (gid >= total4) return;
    int c4 = gid & 31;
    float4 sc = *(const float4*)&ssc[c4 * 4];
    float4 sh = *(const float4*)&ssh[c4 * 4];
    float4 v = ((const float4*)h)[gid];
    float4 o;
    o.x = sc.x * v.x + sh.x;
    o.y = sc.y * v.y + sh.y;
    o.z = sc.z * v.z + sh.z;
    o.w = sc.w * v.w + sh.w;
    ((float4*)dstp)[gid] = o;
}

// ---------------- launch ----------------

extern "C" void kernel_launch(void* const* d_in, const int* in_sizes, int n_in,
                              void* d_out, int out_size, void* d_ws, size_t ws_size,
                              hipStream_t stream) {
    const int*   node_ids = (const int*)d_in[0];
    const int*   src      = (const int*)d_in[1];
    const int*   dst      = (const int*)d_in[2];
    const float* emb      = (const float*)d_in[3];
    const float* Ws       = (const float*)d_in[4];
    const float* bs       = (const float*)d_in[5];
    const float* Rws      = (const float*)d_in[6];
    const float* Rbs      = (const float*)d_in[7];
    const float* gammas   = (const float*)d_in[8];
    const float* betas    = (const float*)d_in[9];

    const int N = in_sizes[0];
    const int E = in_sizes[1];
    const int D = 128;
    const int L = in_sizes[4] / (D * D);

    size_t off = 0;
    auto alloc = [&](size_t bytes) -> void* {
        void* p = (char*)d_ws + off;
        off += (bytes + 255) & ~(size_t)255;
        return p;
    };
    int NS = (N + HSZ - 1) / HSZ;
    int*   deg_rep  = (int*)alloc((size_t)NREP * N * 4);
    unsigned short* out_part = (unsigned short*)alloc((size_t)NS * HB * HSZ * 2);
    int*   rank     = (int*)alloc((size_t)E * 4);
    float* out_norm = (float*)alloc((size_t)N * 4);
    float* in_norm  = (float*)alloc((size_t)N * 4);
    float* nsum     = (float*)alloc((size_t)N * 4);
    int*   row_ptr  = (int*)alloc((size_t)(N + 1) * 4);
    int*   bsumg    = (int*)alloc(64 * 4);
    int*   boffg    = (int*)alloc(64 * 4);
    int2*  col_un   = (int2*)alloc(((size_t)E + 8) * 8);
    float* stats    = (float*)alloc((size_t)L * NBANK * 256 * 4);
    unsigned short* Wt   = (unsigned short*)alloc((size_t)L * D * D * 2);
    unsigned short* Rwt  = (unsigned short*)alloc((size_t)L * D * D * 2);
    unsigned short* x    = (unsigned short*)alloc((size_t)N * D * 2);
    unsigned short* hb0  = (unsigned short*)alloc((size_t)N * D * 2);
    unsigned short* hb1  = (unsigned short*)alloc((size_t)N * D * 2);
    float* h = (float*)d_out;  // fp32 h scratch == output buffer (last layer only)

    hipMemsetAsync(deg_rep, 0, (size_t)NREP * N * 4, stream);
    hipMemsetAsync(stats, 0, (size_t)L * NBANK * 256 * 4, stream);

    // merged prep: src hist | dst degree+rank | emb + weights
    int histBlocks = NS * HB;                       // 128
    int degBlocks = (E + 1023) / 1024;              // 4 edges/thread
    int n32 = N * 32, wtotal = L * D * D;
    int embBlocks = (n32 + TPB - 1) / TPB;
    prep1<<<histBlocks + degBlocks + embBlocks, TPB, 0, stream>>>(
        node_ids, emb, x, n32, Ws, Rws, Wt, Rwt, wtotal,
        src, dst, out_part, deg_rep, rank, E, N, histBlocks, degBlocks);

    int nb = (N + 1023) / 1024;
    scan1_norm<<<nb, 1024, 0, stream>>>(deg_rep, out_part, out_norm, in_norm, row_ptr,
                                        bsumg, N, col_un + E);
    int scatBlocks = (E + 1023) / 1024;
    scatter_kernel<<<scatBlocks, TPB, 0, stream>>>(src, dst, bsumg, nb, boffg, rank,
                                                   out_norm, deg_rep, col_un, E, N,
                                                   scatBlocks * 256);

    int gblocks = (N + GM - 1) / GM;
    // ping-pong buffers: layer 0 x->hb0, layer 1 hb0->hb1, layer 2 hb1->fp32 h
    for (int l = 0; l < L; l++) {
        const unsigned short* Wtl  = Wt  + (size_t)l * D * D;
        const unsigned short* Rwtl = Rwt + (size_t)l * D * D;
        const float* b   = bs  + (size_t)l * D;
        const float* Rb  = Rbs + (size_t)l * D;
        float* st = stats + (size_t)l * NBANK * 256;

        const unsigned short* xin = (l == 0) ? x : ((l & 1) ? hb0 : hb1);
        unsigned short* hbOut = (l < L - 1) ? (((l & 1) == 0) ? hb0 : hb1) : nullptr;
        const float* pst = (l == 0) ? nullptr : stats + (size_t)(l - 1) * NBANK * 256;
        const float* pgm = (l == 0) ? nullptr : gammas + (size_t)(l - 1) * D;
        const float* pbt = (l == 0) ? nullptr : betas  + (size_t)(l - 1) * D;

        if (l == 0) {
            fused_layer_kernel<true, true><<<gblocks, TPB, 0, stream>>>(
                xin, row_ptr, boffg, col_un, in_norm, Wtl, Rwtl, b, Rb,
                nullptr, nullptr, nullptr, (float)N, nsum, h, hbOut, st, N, E);
        } else if (l < L - 1) {
            fused_layer_kernel<false, true><<<gblocks, TPB, 0, stream>>>(
                xin, row_ptr, boffg, col_un, in_norm, Wtl, Rwtl, b, Rb,
                pst, pgm, pbt, (float)N, nsum, h, hbOut, st, N, E);
        } else {
            fused_layer_kernel<false, false><<<gblocks, TPB, 0, stream>>>(
                xin, row_ptr, boffg, col_un, in_norm, Wtl, Rwtl, b, Rb,
                pst, pgm, pbt, (float)N, nsum, h, hbOut, st, N, E);
        }
    }
    // final BN apply on fp32 h (in d_out) -> d_out
    norm_apply_f32<<<(N * 32 + TPB - 1) / TPB, TPB, 0, stream>>>(
        h, stats + (size_t)(L - 1) * NBANK * 256,
        gammas + (size_t)(L - 1) * D, betas + (size_t)(L - 1) * D,
        (float*)d_out, N * 32, (float)N);
}